// Round 1
// baseline (99.454 us; speedup 1.0000x reference)
//
#include <hip/hip_runtime.h>
#include <math.h>

#define EPS 1e-12f
#define NN 8
#define TT 2048
#define DD 512
#define KK 64

typedef short short8 __attribute__((ext_vector_type(8)));
typedef float floatx4 __attribute__((ext_vector_type(4)));

__device__ __forceinline__ unsigned short f2bf(float f) {
    unsigned int u = __float_as_uint(f);
    u += 0x7FFFu + ((u >> 16) & 1u);
    return (unsigned short)(u >> 16);
}
__device__ __forceinline__ unsigned int pack2(float a, float b) {
    return (unsigned int)f2bf(a) | ((unsigned int)f2bf(b) << 16);
}
__device__ __forceinline__ float bf2f_lo(unsigned int u) {
    return __uint_as_float(u << 16);
}
__device__ __forceinline__ float bf2f_hi(unsigned int u) {
    return __uint_as_float(u & 0xFFFF0000u);
}

// ---------------------------------------------------------------------------
// ws layout (float units): unchanged from previous version
//   xb     bf16 [N*T][D]        @ 0        (4194304)
//   aTs    bf16 [N][K][T]       @ 4194304  (524288)
//   part16 bf16 [8tc][512nk][D] @ 4718592  (1048576)
//   asumP  f32  [256blk][64k]   @ 5767168  (16384)
// ---------------------------------------------------------------------------

// kA v2: 1024 threads = 16 waves (4/SIMD, vs 1/SIMD before).
// Wave w: rowgroup g = w&3 (16 t-rows), k-group h = w>>2 (16 k).
// Phase0: wave-contiguous x loads -> bf16 -> {xb, sX fragment slots}, ssq.
// Phase1: MFMA from LDS (sX x sW, both XOR-swizzled conflict-free),
//         cross-wave softmax over k via small LDS buffers.
__global__ __launch_bounds__(1024) void kA(const float* __restrict__ x,
                                           const float* __restrict__ W,
                                           const float* __restrict__ bias,
                                           unsigned short* __restrict__ xb,
                                           unsigned short* __restrict__ aTs,
                                           float* __restrict__ asumP) {
    // sW slot ((s*4+h)*64+lane) ^ ((slot>>4)&7) holds W[h*16+(lane&15)][s*32+(lane>>4)*8..+7]
    __shared__ unsigned short sW[32768];  // 64 KB
    // sX slot ((g*16+s)*4+q)*16 + (l ^ ((s*4+q)&15)) holds x_bf16[g*16+l][s*32+q*8..+7]
    __shared__ unsigned short sX[32768];  // 64 KB
    __shared__ float sSt[64];             // per-row 1/||x||
    __shared__ float sM[4 * 64];          // per-h local max
    __shared__ float sS[4 * 64];          // per-h local expsum
    __shared__ float sRed[256];           // asum partials

    const int tid = threadIdx.x;
    const int w = tid >> 6, lane = tid & 63;
    const int l = lane & 15, q = lane >> 4;
    const int row0 = blockIdx.x * 64;
    const int n = row0 >> 11;
    const int tl0 = row0 & (TT - 1);

    // ---- phase 0: x -> {xb, sX}, per-row ssq ----
    float ssqr[4] = {0.f, 0.f, 0.f, 0.f};
#pragma unroll
    for (int i = 0; i < 8; ++i) {
        const int rl = w * 4 + (i >> 1);          // block-local row 0..63
        const int d0 = (i & 1) * 256 + lane * 4;  // feature offset (4 floats)
        float4 u = *(const float4*)(x + (size_t)(row0 + rl) * DD + d0);
        ssqr[i >> 1] += u.x * u.x + u.y * u.y + u.z * u.z + u.w * u.w;
        uint2 pk;
        pk.x = pack2(u.x, u.y);
        pk.y = pack2(u.z, u.w);
        *(uint2*)(xb + (size_t)(row0 + rl) * DD + d0) = pk;  // raw x bf16
        const int s0 = d0 >> 5, q0 = (d0 >> 3) & 3, half = (d0 >> 2) & 1;
        const int g0 = rl >> 4, lr = rl & 15;
        const int slot = ((g0 * 16 + s0) * 4 + q0) * 16 + (lr ^ ((s0 * 4 + q0) & 15));
        *(uint2*)(sX + slot * 8 + half * 4) = pk;
    }

    // ---- W -> sW (swizzled; 4 slots/thread; L2-hot) ----
#pragma unroll
    for (int j = 0; j < 4; ++j) {
        const int slot = tid * 4 + j;
        const int lw = slot & 15, qw = (slot >> 4) & 3, hw = (slot >> 6) & 3, sw = slot >> 8;
        const float* src = W + (size_t)(hw * 16 + lw) * DD + sw * 32 + qw * 8;
        float4 u0 = *(const float4*)(src);
        float4 u1 = *(const float4*)(src + 4);
        uint4 pk;
        pk.x = pack2(u0.x, u0.y); pk.y = pack2(u0.z, u0.w);
        pk.z = pack2(u1.x, u1.y); pk.w = pack2(u1.z, u1.w);
        const int sl2 = slot ^ ((slot >> 4) & 7);
        *(uint4*)(sW + sl2 * 8) = pk;
    }

    // per-row norm scale -> sSt
#pragma unroll
    for (int rr = 0; rr < 4; ++rr) {
        float ss = ssqr[rr];
#pragma unroll
        for (int m = 1; m <= 32; m <<= 1) ss += __shfl_xor(ss, m, 64);
        if (lane == 0) sSt[w * 4 + rr] = 1.0f / fmaxf(sqrtf(ss), EPS);
    }
    __syncthreads();  // sX, sW, sSt ready

    // ---- phase 1: logits MFMA (this wave: rowgroup g, k-group h) ----
    const int g = w & 3, h = w >> 2;
    floatx4 acc = floatx4{0.f, 0.f, 0.f, 0.f};
#pragma unroll
    for (int s = 0; s < 16; ++s) {
        short8 af = *(const short8*)(sX + (((g * 16 + s) * 4 + q) * 16 + (l ^ ((s * 4 + q) & 15))) * 8);
        const int slot = (s * 4 + h) * 64 + lane;
        short8 wf = *(const short8*)(sW + (slot ^ ((slot >> 4) & 7)) * 8);
        acc = __builtin_amdgcn_mfma_f32_16x16x32_bf16(af, wf, acc, 0, 0, 0);
    }

    // C layout: col = l -> k = h*16+l ; row = 4q+r -> t_loc = g*16+4q+r
    const float bj = bias[h * 16 + l];
    float sr[4], v[4];
#pragma unroll
    for (int r = 0; r < 4; ++r) {
        sr[r] = sSt[g * 16 + 4 * q + r];
        v[r] = acc[r] * sr[r] + bj;
        float m = v[r];
#pragma unroll
        for (int msk = 1; msk <= 8; msk <<= 1) m = fmaxf(m, __shfl_xor(m, msk, 64));
        if (l == 0) sM[h * 64 + g * 16 + 4 * q + r] = m;
    }
    __syncthreads();
    float e[4];
#pragma unroll
    for (int r = 0; r < 4; ++r) {
        const int t = g * 16 + 4 * q + r;
        float M = fmaxf(fmaxf(sM[t], sM[64 + t]), fmaxf(sM[128 + t], sM[192 + t]));
        e[r] = __expf(v[r] - M);
        float ss = e[r];
#pragma unroll
        for (int msk = 1; msk <= 8; msk <<= 1) ss += __shfl_xor(ss, msk, 64);
        if (l == 0) sS[h * 64 + t] = ss;
    }
    __syncthreads();
    float a[4];
#pragma unroll
    for (int r = 0; r < 4; ++r) {
        const int t = g * 16 + 4 * q + r;
        float inv = 1.0f / (sS[t] + sS[64 + t] + sS[128 + t] + sS[192 + t]);
        a[r] = e[r] * inv;
    }

    // aTs[n][k][t] = a * s_t
    {
        uint2 p;
        p.x = pack2(a[0] * sr[0], a[1] * sr[1]);
        p.y = pack2(a[2] * sr[2], a[3] * sr[3]);
        *(uint2*)(aTs + ((size_t)(n * KK + h * 16 + l)) * TT + tl0 + g * 16 + 4 * q) = p;
    }

    // per-block unscaled-a k-sums -> asumP[bid][k]
    float sh = a[0] + a[1] + a[2] + a[3];
    sh += __shfl_xor(sh, 16, 64);
    sh += __shfl_xor(sh, 32, 64);
    if (q == 0) sRed[w * 16 + l] = sh;
    __syncthreads();
    if (tid < 64) {
        const int hh = tid >> 4, ll = tid & 15;
        float s0 = sRed[(hh * 4 + 0) * 16 + ll] + sRed[(hh * 4 + 1) * 16 + ll]
                 + sRed[(hh * 4 + 2) * 16 + ll] + sRed[(hh * 4 + 3) * 16 + ll];
        asumP[(size_t)blockIdx.x * 64 + tid] = s0;
    }
}

// kB v2: dt split 8->16 (32-d tiles): grid 1024 -> 4 blocks/CU (4 waves/SIMD,
// was 2). part16 layout UNCHANGED (finer write tiling only; kC untouched).
// bid = dt*64 + (n*8 + tc): 64 == 0 mod 8, so all 16 dt-blocks sharing an
// (n,tc) aTs/xb slice stay on one XCD (L2 reuse; dt-pairs share 128B lines).
__global__ __launch_bounds__(256) void kB(const unsigned short* __restrict__ xb,
                                          const unsigned short* __restrict__ aTs,
                                          unsigned short* __restrict__ part16) {
    __shared__ unsigned char smem[9216];  // 2x2048 ushort staging | 64x36 f32 transpose
    unsigned short* sX0 = (unsigned short*)smem;
    unsigned short* sX1 = sX0 + 2048;
    float* sT = (float*)smem;

    const int tid = threadIdx.x;
    const int wv = tid >> 6, lane = tid & 63;
    const int l = lane & 15, q = lane >> 4;
    const int bid = blockIdx.x;
    const int low = bid & 63;
    const int n = low >> 3, tc = low & 7, dt = bid >> 6;  // dt in 0..15

    const int ts = tid & 63, dq = tid >> 6;
    const unsigned short* xbase = xb + ((size_t)(n * TT + tc * 256)) * DD + dt * 32 + dq * 8;
    const int g = ts >> 3, t7 = ts & 7;

#define STAGE(S, BUF)                                                          \
    {                                                                          \
        const unsigned short* p_ = xbase + (size_t)((S) * 64 + ts) * DD;       \
        unsigned short vals[8];                                                \
        *(uint4*)(vals) = *(const uint4*)(p_);                                 \
        _Pragma("unroll")                                                      \
        for (int e = 0; e < 8; ++e) {                                          \
            int d_ = dq * 8 + e;                                               \
            (BUF)[d_ * 64 + ((g ^ (d_ & 7)) << 3) + t7] = vals[e];             \
        }                                                                      \
    }

    floatx4 acc[2];
    acc[0] = floatx4{0.f, 0.f, 0.f, 0.f};
    acc[1] = floatx4{0.f, 0.f, 0.f, 0.f};
    const unsigned short* abase = aTs + ((size_t)(n * KK + wv * 16 + l)) * TT + tc * 256;

    STAGE(0, sX0);
    __syncthreads();
#pragma unroll
    for (int s = 0; s < 4; ++s) {
        unsigned short* cur = (s & 1) ? sX1 : sX0;
        unsigned short* nxt = (s & 1) ? sX0 : sX1;
        if (s < 3) {
            if (s == 0) STAGE(1, nxt)
            else if (s == 1) STAGE(2, nxt)
            else STAGE(3, nxt)
        }
#pragma unroll
        for (int kb = 0; kb < 2; ++kb) {
            short8 af = *(const short8*)(abase + s * 64 + kb * 32 + q * 8);
            int gg = q + 4 * kb;
#pragma unroll
            for (int nt = 0; nt < 2; ++nt) {
                int d = nt * 16 + l;
                short8 bf = *(const short8*)(cur + d * 64 + ((gg ^ (d & 7)) << 3));
                acc[nt] = __builtin_amdgcn_mfma_f32_16x16x32_bf16(af, bf, acc[nt], 0, 0, 0);
            }
        }
        __syncthreads();
    }
#undef STAGE

    // transpose C through LDS -> coalesced bf16 stores
#pragma unroll
    for (int nt = 0; nt < 2; ++nt)
#pragma unroll
        for (int r = 0; r < 4; ++r)
            sT[(wv * 16 + 4 * q + r) * 36 + nt * 16 + l] = acc[nt][r];
    __syncthreads();

    unsigned short* pbase = part16 + ((size_t)(tc * 512 + n * KK)) * DD + dt * 32;
    const int fq = tid & 7, kr = tid >> 3;
#pragma unroll
    for (int i = 0; i < 2; ++i) {
        int k = i * 32 + kr;
        float4 val = *(float4*)(sT + k * 36 + fq * 4);
        uint2 o;
        o.x = pack2(val.x, val.y);
        o.y = pack2(val.z, val.w);
        *(uint2*)(pbase + (size_t)k * DD + fq * 4) = o;
    }
}

// kC: unchanged. asum = sum(asumP); val = sum_tc part16 - asum*c; intra-norm +
// global-norm fold (global norm over 64 intra-normalized clusters == 8).
__global__ __launch_bounds__(128) void kC(const unsigned short* __restrict__ part16,
                                          const float* __restrict__ asumP,
                                          const float* __restrict__ cent,
                                          float* __restrict__ out) {
    __shared__ float red[2];
    __shared__ float sAsum;
    const int nk = blockIdx.x;
    const int n = nk >> 6, k = nk & 63;
    const int tid = threadIdx.x;

    if (tid < 32) {
        float p = asumP[(size_t)(n * 32 + tid) * 64 + k];
#pragma unroll
        for (int m = 16; m >= 1; m >>= 1) p += __shfl_xor(p, m, 64);
        if (tid == 0) sAsum = p;
    }
    __syncthreads();
    float as = sAsum;

    float4 cc = ((const float4*)(cent + (size_t)k * DD))[tid];
    float4 a4 = make_float4(-as * cc.x, -as * cc.y, -as * cc.z, -as * cc.w);
#pragma unroll
    for (int tc = 0; tc < 8; ++tc) {
        uint2 p = ((const uint2*)(part16 + ((size_t)(tc * 512 + nk)) * DD))[tid];
        a4.x += bf2f_lo(p.x); a4.y += bf2f_hi(p.x);
        a4.z += bf2f_lo(p.y); a4.w += bf2f_hi(p.y);
    }
    float ssq = a4.x * a4.x + a4.y * a4.y + a4.z * a4.z + a4.w * a4.w;
#pragma unroll
    for (int m = 32; m >= 1; m >>= 1) ssq += __shfl_xor(ssq, m, 64);
    if ((tid & 63) == 0) red[tid >> 6] = ssq;
    __syncthreads();
    float nr = sqrtf(red[0] + red[1]);
    float sc = 1.0f / (fmaxf(nr, EPS) * 8.0f);
    a4.x *= sc; a4.y *= sc; a4.z *= sc; a4.w *= sc;
    ((float4*)(out + (size_t)nk * DD))[tid] = a4;
}

extern "C" void kernel_launch(void* const* d_in, const int* in_sizes, int n_in,
                              void* d_out, int out_size, void* d_ws, size_t ws_size,
                              hipStream_t stream) {
    const float* x    = (const float*)d_in[0];
    const float* W    = (const float*)d_in[1];
    const float* b    = (const float*)d_in[2];
    const float* cent = (const float*)d_in[3];
    float* out = (float*)d_out;

    float* w = (float*)d_ws;
    unsigned short* xb     = (unsigned short*)(w + 0);
    unsigned short* aTs    = (unsigned short*)(w + 4194304);
    unsigned short* part16 = (unsigned short*)(w + 4718592);
    float* asumP = w + 5767168;

    hipLaunchKernelGGL(kA, dim3(256), dim3(1024), 0, stream, x, W, b, xb, aTs, asumP);
    hipLaunchKernelGGL(kB, dim3(1024), dim3(256), 0, stream, xb, aTs, part16);
    hipLaunchKernelGGL(kC, dim3(512), dim3(128), 0, stream, part16, asumP, cent, out);
}

// Round 2
// 97.023 us; speedup vs baseline: 1.0251x; 1.0251x over previous
//
#include <hip/hip_runtime.h>
#include <math.h>

#define EPS 1e-12f
#define NN 8
#define TT 2048
#define DD 512
#define KK 64

typedef short short8 __attribute__((ext_vector_type(8)));
typedef float floatx4 __attribute__((ext_vector_type(4)));

__device__ __forceinline__ unsigned short f2bf(float f) {
    unsigned int u = __float_as_uint(f);
    u += 0x7FFFu + ((u >> 16) & 1u);
    return (unsigned short)(u >> 16);
}
__device__ __forceinline__ unsigned int pack2(float a, float b) {
    return (unsigned int)f2bf(a) | ((unsigned int)f2bf(b) << 16);
}
__device__ __forceinline__ float bf2f_lo(unsigned int u) {
    return __uint_as_float(u << 16);
}
__device__ __forceinline__ float bf2f_hi(unsigned int u) {
    return __uint_as_float(u & 0xFFFF0000u);
}

// sX row-swizzle: row l of slot-group (s,q) lives at F = l ^ ((s*4+q)&15),
// refined with F ^= (F&8)>>1 (bit3 -> bit2) so the PV u16-gather (which
// walks F at fixed low bits) spreads over 8 bank-quads instead of 2.
__device__ __forceinline__ int lperm(int l, int sq) {
    int F = l ^ (sq & 15);
    return F ^ ((F & 8) >> 1);
}

// ---------------------------------------------------------------------------
// ws layout (float units):
//   part  bf16 [32c][512 nk][D] @ 0        (4194304 floats = 16 MB)
//   asumP f32  [256 blk][64 k]  @ 4194304  (16384 floats)
// xb / aTs eliminated by fusion (was 40% of HBM traffic).
// ---------------------------------------------------------------------------

// kF: fused normalize + logits + softmax + PV partial, one block per
// (n = bid>>5, c = bid&31) 64-row t-chunk. 1024 threads = 16 waves.
//   phase0: x -> bf16 -> sX (swizzled fragment slots), row ssq; W -> sW.
//   logits: wave (g=w&3, h=w>>2): rows g*16.., k's h*16.. (round-1 code).
//   softmax: cross-wave max/sum via sM/sS; aS[k][t] = a*s_t -> LDS.
//   PV: wave (kg=w&3, dt8=w>>2): C[k in kg*16..][d in dt8*128..]
//       A = aS (b128), B = x from sX via 8x ds_read_u16 gather.
//   out: part[c][n*64+k][d] bf16, asumP[bid][k].
__global__ __launch_bounds__(1024) void kF(const float* __restrict__ x,
                                           const float* __restrict__ W,
                                           const float* __restrict__ bias,
                                           unsigned short* __restrict__ part,
                                           float* __restrict__ asumP) {
    __shared__ unsigned short sX[32768];  // 64 KB: 4096 slots * 16 B
    __shared__ unsigned short sW[32768];  // 64 KB (round-1 layout)
    __shared__ unsigned short sA[64 * 72];  // aS[k][t], row stride 72 (pad)
    __shared__ float sSt[64];
    __shared__ float sM[256];
    __shared__ float sS[256];
    __shared__ float sRed[256];

    const int tid = threadIdx.x;
    const int w = tid >> 6, lane = tid & 63;
    const int l = lane & 15, q = lane >> 4;
    const int bid = blockIdx.x;
    const int row0 = bid * 64;
    const int n = bid >> 5, c = bid & 31;

    // ---- phase 0: x -> {sX}, per-row ssq ----
    float ssqr[4] = {0.f, 0.f, 0.f, 0.f};
#pragma unroll
    for (int i = 0; i < 8; ++i) {
        const int rl = w * 4 + (i >> 1);
        const int d0 = (i & 1) * 256 + lane * 4;
        float4 u = *(const float4*)(x + (size_t)(row0 + rl) * DD + d0);
        ssqr[i >> 1] += u.x * u.x + u.y * u.y + u.z * u.z + u.w * u.w;
        uint2 pk;
        pk.x = pack2(u.x, u.y);
        pk.y = pack2(u.z, u.w);
        const int s0 = d0 >> 5, q0 = (d0 >> 3) & 3, half = (d0 >> 2) & 1;
        const int g0 = rl >> 4, lr = rl & 15;
        const int slot = ((g0 * 16 + s0) * 4 + q0) * 16 + lperm(lr, s0 * 4 + q0);
        *(uint2*)(sX + slot * 8 + half * 4) = pk;
    }

    // ---- W -> sW (swizzled; 4 slots/thread; L2-hot) ----
#pragma unroll
    for (int j = 0; j < 4; ++j) {
        const int slot = tid * 4 + j;
        const int lw = slot & 15, qw = (slot >> 4) & 3, hw = (slot >> 6) & 3, sw_ = slot >> 8;
        const float* src = W + (size_t)(hw * 16 + lw) * DD + sw_ * 32 + qw * 8;
        float4 u0 = *(const float4*)(src);
        float4 u1 = *(const float4*)(src + 4);
        uint4 pk;
        pk.x = pack2(u0.x, u0.y); pk.y = pack2(u0.z, u0.w);
        pk.z = pack2(u1.x, u1.y); pk.w = pack2(u1.z, u1.w);
        const int sl2 = slot ^ ((slot >> 4) & 7);
        *(uint4*)(sW + sl2 * 8) = pk;
    }

    // per-row norm scale -> sSt
#pragma unroll
    for (int rr = 0; rr < 4; ++rr) {
        float ss = ssqr[rr];
#pragma unroll
        for (int m = 1; m <= 32; m <<= 1) ss += __shfl_xor(ss, m, 64);
        if (lane == 0) sSt[w * 4 + rr] = 1.0f / fmaxf(sqrtf(ss), EPS);
    }
    __syncthreads();  // sX, sW, sSt ready

    // ---- logits MFMA: wave (g,h) ----
    const int g = w & 3, h = w >> 2;
    floatx4 acc = floatx4{0.f, 0.f, 0.f, 0.f};
#pragma unroll
    for (int s = 0; s < 16; ++s) {
        short8 af = *(const short8*)(sX + (((g * 16 + s) * 4 + q) * 16 + lperm(l, s * 4 + q)) * 8);
        const int slot = (s * 4 + h) * 64 + lane;
        short8 wf = *(const short8*)(sW + (slot ^ ((slot >> 4) & 7)) * 8);
        acc = __builtin_amdgcn_mfma_f32_16x16x32_bf16(af, wf, acc, 0, 0, 0);
    }

    // C layout: col = l -> k = h*16+l ; row = 4q+r -> t_loc = g*16+4q+r
    const float bj = bias[h * 16 + l];
    float sr[4], v[4];
#pragma unroll
    for (int r = 0; r < 4; ++r) {
        sr[r] = sSt[g * 16 + 4 * q + r];
        v[r] = acc[r] * sr[r] + bj;
        float m = v[r];
#pragma unroll
        for (int msk = 1; msk <= 8; msk <<= 1) m = fmaxf(m, __shfl_xor(m, msk, 64));
        if (l == 0) sM[h * 64 + g * 16 + 4 * q + r] = m;
    }
    __syncthreads();
    float e[4];
#pragma unroll
    for (int r = 0; r < 4; ++r) {
        const int t = g * 16 + 4 * q + r;
        float M = fmaxf(fmaxf(sM[t], sM[64 + t]), fmaxf(sM[128 + t], sM[192 + t]));
        e[r] = __expf(v[r] - M);
        float ss = e[r];
#pragma unroll
        for (int msk = 1; msk <= 8; msk <<= 1) ss += __shfl_xor(ss, msk, 64);
        if (l == 0) sS[h * 64 + t] = ss;
    }
    __syncthreads();
    float a[4];
#pragma unroll
    for (int r = 0; r < 4; ++r) {
        const int t = g * 16 + 4 * q + r;
        float inv = 1.0f / (sS[t] + sS[64 + t] + sS[128 + t] + sS[192 + t]);
        a[r] = e[r] * inv;
    }

    // aS[k][t] = a * s_t -> LDS (PV A-operand)
    {
        uint2 p;
        p.x = pack2(a[0] * sr[0], a[1] * sr[1]);
        p.y = pack2(a[2] * sr[2], a[3] * sr[3]);
        *(uint2*)(sA + (h * 16 + l) * 72 + g * 16 + 4 * q) = p;
    }

    // per-block unscaled-a k-sums
    float sh = a[0] + a[1] + a[2] + a[3];
    sh += __shfl_xor(sh, 16, 64);
    sh += __shfl_xor(sh, 32, 64);
    if (q == 0) sRed[(h * 16 + l) * 4 + g] = sh;
    __syncthreads();  // sA + sRed ready; sX still intact
    if (tid < 64) {
        asumP[(size_t)bid * 64 + tid] =
            sRed[tid * 4] + sRed[tid * 4 + 1] + sRed[tid * 4 + 2] + sRed[tid * 4 + 3];
    }

    // ---- PV: wave (kg, dt8) owns k = kg*16..+15, d = dt8*128..+127 ----
    const int kg = w & 3, dt8 = w >> 2;
    floatx4 pacc[8];
#pragma unroll
    for (int j = 0; j < 8; ++j) pacc[j] = floatx4{0.f, 0.f, 0.f, 0.f};
#pragma unroll
    for (int kk = 0; kk < 2; ++kk) {
        short8 af = *(const short8*)(sA + (kg * 16 + l) * 72 + kk * 32 + q * 8);
        const int gP = kk * 2 + (q >> 1);
        const int lPb = (q & 1) * 8;
#pragma unroll
        for (int j = 0; j < 8; ++j) {
            const int d = (dt8 * 8 + j) * 16 + l;
            const int sP = d >> 5, qP = (d >> 3) & 3, eo = d & 7;
            const int swP = (sP * 4 + qP) & 15;
            const int Fhi = lPb ^ (swP & 8);
            const int eX = (swP & 7) ^ ((Fhi & 8) >> 1);
            const int base = (((gP * 16 + sP) * 4 + qP) * 16 + Fhi) * 8 + eo;
            union { unsigned short u[8]; short8 v; } bu;
#pragma unroll
            for (int ee = 0; ee < 8; ++ee) bu.u[ee] = sX[base + ((ee ^ eX) << 3)];
            pacc[j] = __builtin_amdgcn_mfma_f32_16x16x32_bf16(af, bu.v, pacc[j], 0, 0, 0);
        }
    }

    // ---- epilogue: pacc -> part (shfl-pair bf16 pack, even lanes store) ----
    unsigned short* pb = part + ((size_t)(c * 512 + n * KK + kg * 16 + q * 4)) * DD + dt8 * 128 + l;
#pragma unroll
    for (int j = 0; j < 8; ++j) {
#pragma unroll
        for (int r = 0; r < 4; ++r) {
            float v1 = __shfl_xor(pacc[j][r], 1, 64);
            if (!(l & 1)) {
                unsigned int pk = pack2(pacc[j][r], v1);
                *(unsigned int*)(pb + (size_t)r * DD + j * 16) = pk;
            }
        }
    }
}

// kC: asum = sum(asumP over 32 c-blocks); val = sum_c part - asum*cent;
// intra-norm; global norm over 64 unit clusters == sqrt(64) = 8 (folded).
__global__ __launch_bounds__(128) void kC(const unsigned short* __restrict__ part,
                                          const float* __restrict__ asumP,
                                          const float* __restrict__ cent,
                                          float* __restrict__ out) {
    __shared__ float red[2];
    __shared__ float sAsum;
    const int nk = blockIdx.x;
    const int n = nk >> 6, k = nk & 63;
    const int tid = threadIdx.x;

    if (tid < 32) {
        float p = asumP[(size_t)(n * 32 + tid) * 64 + k];
#pragma unroll
        for (int m = 16; m >= 1; m >>= 1) p += __shfl_xor(p, m, 64);
        if (tid == 0) sAsum = p;
    }
    __syncthreads();
    float as = sAsum;

    float4 cc = ((const float4*)(cent + (size_t)k * DD))[tid];
    float4 a4 = make_float4(-as * cc.x, -as * cc.y, -as * cc.z, -as * cc.w);
#pragma unroll
    for (int tc = 0; tc < 32; ++tc) {
        uint2 p = ((const uint2*)(part + ((size_t)(tc * 512 + nk)) * DD))[tid];
        a4.x += bf2f_lo(p.x); a4.y += bf2f_hi(p.x);
        a4.z += bf2f_lo(p.y); a4.w += bf2f_hi(p.y);
    }
    float ssq = a4.x * a4.x + a4.y * a4.y + a4.z * a4.z + a4.w * a4.w;
#pragma unroll
    for (int m = 32; m >= 1; m >>= 1) ssq += __shfl_xor(ssq, m, 64);
    if ((tid & 63) == 0) red[tid >> 6] = ssq;
    __syncthreads();
    float nr = sqrtf(red[0] + red[1]);
    float sc = 1.0f / (fmaxf(nr, EPS) * 8.0f);
    a4.x *= sc; a4.y *= sc; a4.z *= sc; a4.w *= sc;
    ((float4*)(out + (size_t)nk * DD))[tid] = a4;
}

extern "C" void kernel_launch(void* const* d_in, const int* in_sizes, int n_in,
                              void* d_out, int out_size, void* d_ws, size_t ws_size,
                              hipStream_t stream) {
    const float* x    = (const float*)d_in[0];
    const float* W    = (const float*)d_in[1];
    const float* b    = (const float*)d_in[2];
    const float* cent = (const float*)d_in[3];
    float* out = (float*)d_out;

    float* w = (float*)d_ws;
    unsigned short* part = (unsigned short*)(w + 0);
    float* asumP = w + 4194304;

    hipLaunchKernelGGL(kF, dim3(256), dim3(1024), 0, stream, x, W, b, part, asumP);
    hipLaunchKernelGGL(kC, dim3(512), dim3(128), 0, stream, part, asumP, cent, out);
}

// Round 3
// 95.291 us; speedup vs baseline: 1.0437x; 1.0182x over previous
//
#include <hip/hip_runtime.h>
#include <math.h>

#define EPS 1e-12f
#define NN 8
#define TT 2048
#define DD 512
#define KK 64

typedef short short8 __attribute__((ext_vector_type(8)));
typedef float floatx4 __attribute__((ext_vector_type(4)));

__device__ __forceinline__ unsigned short f2bf(float f) {
    unsigned int u = __float_as_uint(f);
    u += 0x7FFFu + ((u >> 16) & 1u);
    return (unsigned short)(u >> 16);
}
__device__ __forceinline__ unsigned int pack2(float a, float b) {
    return (unsigned int)f2bf(a) | ((unsigned int)f2bf(b) << 16);
}
__device__ __forceinline__ float bf2f_lo(unsigned int u) {
    return __uint_as_float(u << 16);
}
__device__ __forceinline__ float bf2f_hi(unsigned int u) {
    return __uint_as_float(u & 0xFFFF0000u);
}

// ---------------------------------------------------------------------------
// ws layout (float units):
//   xb     bf16 [N*T][D]        @ 0        (4194304)   raw x, bf16
//   aTs    bf16 [N][K][T]       @ 4194304  (524288)    a * s_t
//   part16 bf16 [8tc][512nk][D] @ 4718592  (1048576)   vlad partials, bf16
//   asumP  f32  [256blk][64k]   @ 5767168  (16384)     per-block unscaled a sums
// total 5783552 floats = 23.1 MB
// ---------------------------------------------------------------------------

// kA: fused W->bf16 (LDS, fragment-packed) + L2-norm + assignment softmax.
// Block = 64 t-rows (4 waves x 16 rows); grid 256 (1 block/CU).
// Writes xb (raw bf16 x), aTs[k][t] = a*s_t, asumP[block][k].
//
// v3 change vs round-0: sW slots are XOR-swizzled (slot ^= (slot>>4)&7) on
// BOTH the staging write and the MFMA read. Round-0's write pattern
// (wdst = sW + tid*256B) was lane-invariant in bank index -> full-wave
// same-bank-quad serialization on every ds_write_b128 (G4). Swizzled
// write spreads each wave instr over all 32 banks (8 rows = minimum for
// 1 KB); read side stays at the 8-row minimum too.
__global__ __launch_bounds__(256) void kA(const float* __restrict__ x,
                                          const float* __restrict__ W,
                                          const float* __restrict__ bias,
                                          unsigned short* __restrict__ xb,
                                          unsigned short* __restrict__ aTs,
                                          float* __restrict__ asumP) {
    // sW: fragment-packed Wb. Logical slot ((s*4+h)*64 + lane) holds
    // W[h*16 + (lane&15)][s*32 + (lane>>4)*8 .. +7]; stored at slot^((slot>>4)&7).
    __shared__ unsigned short sW[32768];  // 64 KB
    __shared__ float sRed[256];

    const int tid = threadIdx.x;

    const int w = tid >> 6, lane = tid & 63;
    const int l = lane & 15, q = lane >> 4;
    const int row0 = blockIdx.x * 64 + w * 16;
    const int row = row0 + l;
    const int n = row0 >> 11;
    const int tl0 = row0 & (TT - 1);

    const float* xr = x + (size_t)row * DD;
    unsigned short* xo = xb + (size_t)row * DD;
    short8 fragA[16];
    float ssq = 0.0f;
#pragma unroll
    for (int s = 0; s < 16; ++s) {
        float4 u0 = *(const float4*)(xr + s * 32 + q * 8);
        float4 u1 = *(const float4*)(xr + s * 32 + q * 8 + 4);
        ssq += u0.x*u0.x + u0.y*u0.y + u0.z*u0.z + u0.w*u0.w
             + u1.x*u1.x + u1.y*u1.y + u1.z*u1.z + u1.w*u1.w;
        uint4 pk;
        pk.x = pack2(u0.x, u0.y); pk.y = pack2(u0.z, u0.w);
        pk.z = pack2(u1.x, u1.y); pk.w = pack2(u1.z, u1.w);
        union { uint4 u; short8 s8; } cvt; cvt.u = pk;
        fragA[s] = cvt.s8;
        *(uint4*)(xo + s * 32 + q * 8) = pk;
    }

    // ---- W -> LDS prologue (L2-hot; 128 elems/thread), swizzled writes ----
    {
        const int sp = tid >> 4, hp = (tid >> 2) & 3, qp = tid & 3;
        const float* wsrc = W + (size_t)(hp * 16) * DD + sp * 32 + qp * 8;
#pragma unroll
        for (int j = 0; j < 16; ++j) {
            float4 u0 = *(const float4*)(wsrc + (size_t)j * DD);
            float4 u1 = *(const float4*)(wsrc + (size_t)j * DD + 4);
            uint4 pk;
            pk.x = pack2(u0.x, u0.y); pk.y = pack2(u0.z, u0.w);
            pk.z = pack2(u1.x, u1.y); pk.w = pack2(u1.z, u1.w);
            // logical slot = tid*16 + j ; swizzle XOR = (slot>>4)&7 = tid&7
            *(uint4*)(sW + (size_t)(tid * 16 + (j ^ (tid & 7))) * 8) = pk;
        }
    }

    ssq += __shfl_xor(ssq, 16, 64);
    ssq += __shfl_xor(ssq, 32, 64);
    float st = 1.0f / fmaxf(sqrtf(ssq), EPS);

    __syncthreads();  // sW ready

    // ---- logits MFMA: B-frags from LDS (swizzled reads) ----
    floatx4 acc[4];
#pragma unroll
    for (int h = 0; h < 4; ++h) acc[h] = floatx4{0.f, 0.f, 0.f, 0.f};
#pragma unroll
    for (int s = 0; s < 16; ++s) {
#pragma unroll
        for (int h = 0; h < 4; ++h) {
            const int slot = (s * 4 + h) * 64 + lane;
            short8 wf = *(const short8*)(sW + (size_t)(slot ^ ((slot >> 4) & 7)) * 8);
            acc[h] = __builtin_amdgcn_mfma_f32_16x16x32_bf16(fragA[s], wf, acc[h], 0, 0, 0);
        }
    }

    float sr[4];
#pragma unroll
    for (int r = 0; r < 4; ++r) sr[r] = __shfl(st, 4 * q + r, 64);
    float bj[4];
#pragma unroll
    for (int h = 0; h < 4; ++h) bj[h] = bias[h * 16 + l];

    float av[4][4];  // [h][r]
#pragma unroll
    for (int r = 0; r < 4; ++r) {
        float v0 = acc[0][r] * sr[r] + bj[0], v1 = acc[1][r] * sr[r] + bj[1];
        float v2 = acc[2][r] * sr[r] + bj[2], v3 = acc[3][r] * sr[r] + bj[3];
        float m = fmaxf(fmaxf(v0, v1), fmaxf(v2, v3));
#pragma unroll
        for (int msk = 1; msk <= 8; msk <<= 1) m = fmaxf(m, __shfl_xor(m, msk, 64));
        float e0 = __expf(v0 - m), e1 = __expf(v1 - m), e2 = __expf(v2 - m), e3 = __expf(v3 - m);
        float ss = e0 + e1 + e2 + e3;
#pragma unroll
        for (int msk = 1; msk <= 8; msk <<= 1) ss += __shfl_xor(ss, msk, 64);
        float inv = 1.0f / ss;
        av[0][r] = e0 * inv; av[1][r] = e1 * inv; av[2][r] = e2 * inv; av[3][r] = e3 * inv;
    }

    // aTs[n][k][t] = a * s_t  (t = tl0 + 4q + r, k = h*16 + l)
#pragma unroll
    for (int h = 0; h < 4; ++h) {
        uint2 p;
        p.x = pack2(av[h][0] * sr[0], av[h][1] * sr[1]);
        p.y = pack2(av[h][2] * sr[2], av[h][3] * sr[3]);
        *(uint2*)(aTs + ((size_t)(n * KK + h * 16 + l)) * TT + tl0 + 4 * q) = p;
    }

    // per-block unscaled-a k-sums -> asumP[bid][k]
#pragma unroll
    for (int h = 0; h < 4; ++h) {
        float sh = av[h][0] + av[h][1] + av[h][2] + av[h][3];
        sh += __shfl_xor(sh, 16, 64);
        sh += __shfl_xor(sh, 32, 64);
        if (q == 0) sRed[w * 64 + h * 16 + l] = sh;
    }
    __syncthreads();
    if (tid < 64) {
        float s0 = sRed[tid] + sRed[64 + tid] + sRed[128 + tid] + sRed[192 + tid];
        asumP[(size_t)blockIdx.x * 64 + tid] = s0;
    }
}

// kB: part16[tc][n*64+k][d] = sum_{t in 256-chunk} aTs[k][t] * xb[t][d]
// bid = dt*64 + (n*8 + tc): bid%8 == tc -> all 8 dt-blocks sharing an
// (n,tc) aTs/xb slice land on the same XCD (L2 reuse; aTs fetched once).
__global__ __launch_bounds__(256) void kB(const unsigned short* __restrict__ xb,
                                          const unsigned short* __restrict__ aTs,
                                          unsigned short* __restrict__ part16) {
    __shared__ unsigned char smem[17408];  // 2x4096 ushort staging | 64x68 f32 transpose
    unsigned short* sX0 = (unsigned short*)smem;
    unsigned short* sX1 = sX0 + 4096;
    float* sT = (float*)smem;

    const int tid = threadIdx.x;
    const int wv = tid >> 6, lane = tid & 63;
    const int l = lane & 15, q = lane >> 4;
    const int bid = blockIdx.x;
    const int low = bid & 63;
    const int n = low >> 3, tc = low & 7, dt = bid >> 6;

    const int ts = tid & 63, dq = tid >> 6;
    const unsigned short* xbase = xb + ((size_t)(n * TT + tc * 256)) * DD + dt * 64 + dq * 16;
    const int g = ts >> 3, t7 = ts & 7;

#define STAGE(S, BUF)                                                          \
    {                                                                          \
        const unsigned short* p_ = xbase + (size_t)((S) * 64 + ts) * DD;       \
        unsigned short vals[16];                                               \
        *(uint4*)(vals) = *(const uint4*)(p_);                                 \
        *(uint4*)(vals + 8) = *(const uint4*)(p_ + 8);                         \
        _Pragma("unroll")                                                      \
        for (int e = 0; e < 16; ++e) {                                         \
            int d_ = dq * 16 + e;                                              \
            (BUF)[d_ * 64 + ((g ^ (d_ & 7)) << 3) + t7] = vals[e];             \
        }                                                                      \
    }

    floatx4 acc[4];
#pragma unroll
    for (int nt = 0; nt < 4; ++nt) acc[nt] = floatx4{0.f, 0.f, 0.f, 0.f};
    const unsigned short* abase = aTs + ((size_t)(n * KK + wv * 16 + l)) * TT + tc * 256;

    STAGE(0, sX0);
    __syncthreads();
#pragma unroll
    for (int s = 0; s < 4; ++s) {
        unsigned short* cur = (s & 1) ? sX1 : sX0;
        unsigned short* nxt = (s & 1) ? sX0 : sX1;
        if (s < 3) {
            if (s == 0) STAGE(1, nxt)
            else if (s == 1) STAGE(2, nxt)
            else STAGE(3, nxt)
        }
#pragma unroll
        for (int kb = 0; kb < 2; ++kb) {
            short8 af = *(const short8*)(abase + s * 64 + kb * 32 + q * 8);
            int gg = q + 4 * kb;
#pragma unroll
            for (int nt = 0; nt < 4; ++nt) {
                int d = nt * 16 + l;
                short8 bf = *(const short8*)(cur + d * 64 + ((gg ^ (d & 7)) << 3));
                acc[nt] = __builtin_amdgcn_mfma_f32_16x16x32_bf16(af, bf, acc[nt], 0, 0, 0);
            }
        }
        __syncthreads();
    }
#undef STAGE

    // transpose C through LDS -> coalesced bf16 stores
#pragma unroll
    for (int nt = 0; nt < 4; ++nt)
#pragma unroll
        for (int r = 0; r < 4; ++r)
            sT[(wv * 16 + 4 * q + r) * 68 + nt * 16 + l] = acc[nt][r];
    __syncthreads();

    unsigned short* pbase = part16 + ((size_t)(tc * 512 + n * KK)) * DD + dt * 64;
    const int fq = tid & 15, kr = tid >> 4;
#pragma unroll
    for (int i = 0; i < 4; ++i) {
        int k = i * 16 + kr;
        float4 val = *(float4*)(sT + k * 68 + fq * 4);
        uint2 o;
        o.x = pack2(val.x, val.y);
        o.y = pack2(val.z, val.w);
        *(uint2*)(pbase + (size_t)k * DD + fq * 4) = o;
    }
}

// kC: asum = sum(asumP); val = sum_tc part16 - asum*c; intra-norm + global-norm
// fold -> out. Global norm over 64 intra-normalized clusters is exactly
// sqrt(64)=8 (each cluster contributes 1.0 +- <1e-6 rel).
__global__ __launch_bounds__(128) void kC(const unsigned short* __restrict__ part16,
                                          const float* __restrict__ asumP,
                                          const float* __restrict__ cent,
                                          float* __restrict__ out) {
    __shared__ float red[2];
    __shared__ float sAsum;
    const int nk = blockIdx.x;
    const int n = nk >> 6, k = nk & 63;
    const int tid = threadIdx.x;

    if (tid < 32) {
        float p = asumP[(size_t)(n * 32 + tid) * 64 + k];
#pragma unroll
        for (int m = 16; m >= 1; m >>= 1) p += __shfl_xor(p, m, 64);
        if (tid == 0) sAsum = p;
    }
    __syncthreads();
    float as = sAsum;

    float4 cc = ((const float4*)(cent + (size_t)k * DD))[tid];
    float4 a4 = make_float4(-as * cc.x, -as * cc.y, -as * cc.z, -as * cc.w);
#pragma unroll
    for (int tc = 0; tc < 8; ++tc) {
        uint2 p = ((const uint2*)(part16 + ((size_t)(tc * 512 + nk)) * DD))[tid];
        a4.x += bf2f_lo(p.x); a4.y += bf2f_hi(p.x);
        a4.z += bf2f_lo(p.y); a4.w += bf2f_hi(p.y);
    }
    float ssq = a4.x*a4.x + a4.y*a4.y + a4.z*a4.z + a4.w*a4.w;
#pragma unroll
    for (int m = 32; m >= 1; m >>= 1) ssq += __shfl_xor(ssq, m, 64);
    if ((tid & 63) == 0) red[tid >> 6] = ssq;
    __syncthreads();
    float nr = sqrtf(red[0] + red[1]);
    float sc = 1.0f / (fmaxf(nr, EPS) * 8.0f);
    a4.x *= sc; a4.y *= sc; a4.z *= sc; a4.w *= sc;
    ((float4*)(out + (size_t)nk * DD))[tid] = a4;
}

extern "C" void kernel_launch(void* const* d_in, const int* in_sizes, int n_in,
                              void* d_out, int out_size, void* d_ws, size_t ws_size,
                              hipStream_t stream) {
    const float* x    = (const float*)d_in[0];
    const float* W    = (const float*)d_in[1];
    const float* b    = (const float*)d_in[2];
    const float* cent = (const float*)d_in[3];
    float* out = (float*)d_out;

    float* w = (float*)d_ws;
    unsigned short* xb     = (unsigned short*)(w + 0);
    unsigned short* aTs    = (unsigned short*)(w + 4194304);
    unsigned short* part16 = (unsigned short*)(w + 4718592);
    float* asumP = w + 5767168;

    hipLaunchKernelGGL(kA, dim3(256), dim3(256), 0, stream, x, W, b, xb, aTs, asumP);
    hipLaunchKernelGGL(kB, dim3(512), dim3(256), 0, stream, xb, aTs, part16);
    hipLaunchKernelGGL(kC, dim3(512), dim3(128), 0, stream, part16, asumP, cent, out);
}